// Round 7
// baseline (346.590 us; speedup 1.0000x reference)
//
#include <hip/hip_runtime.h>

#define ZN 131072          // B*H*W rows
#define DD 64              // embedding dim
#define KK 1024            // codebook entries
#define BSTRIDE 262144     // 64*64*64 (per-batch stride in z)
#define DSTRIDE 4096       // per-d stride in z (H*W)
#define ZQ_ELEMS 8388608   // 32*64*64*64
#define TAU 2e-4f

// ---- workspace layout ----
// [0,8)                double   loss accumulator
// [8,12)               unsigned done-block counter
// [16,4112)            float    csq32[1024]    (numpy-emulated fp32)
// [2363408,2625552)    ushort   cbB[64][2][2][64][8]  bf16 hi/lo B-fragments
#define WS_CSQ_OFF   16
#define WS_CBB_OFF   2363408

typedef __attribute__((ext_vector_type(8))) short short8;
typedef __attribute__((ext_vector_type(4))) float f32x4;

// round-to-nearest-even fp32 -> bf16 (data has no NaN/Inf)
__device__ __forceinline__ unsigned short f2bf_rne(float x) {
    unsigned u = __float_as_uint(x);
    return (unsigned short)((u + 0x7fffu + ((u >> 16) & 1u)) >> 16);
}

// numpy-emulated fp32 sum of a[i]^2 over 64 elems (pairwise, 8 accumulators).
__device__ __forceinline__ float np_sumsq64(const float* a) {
    float r0 = __fmul_rn(a[0], a[0]), r1 = __fmul_rn(a[1], a[1]);
    float r2 = __fmul_rn(a[2], a[2]), r3 = __fmul_rn(a[3], a[3]);
    float r4 = __fmul_rn(a[4], a[4]), r5 = __fmul_rn(a[5], a[5]);
    float r6 = __fmul_rn(a[6], a[6]), r7 = __fmul_rn(a[7], a[7]);
#pragma unroll
    for (int i = 8; i < 64; i += 8) {
        r0 = __fadd_rn(r0, __fmul_rn(a[i + 0], a[i + 0]));
        r1 = __fadd_rn(r1, __fmul_rn(a[i + 1], a[i + 1]));
        r2 = __fadd_rn(r2, __fmul_rn(a[i + 2], a[i + 2]));
        r3 = __fadd_rn(r3, __fmul_rn(a[i + 3], a[i + 3]));
        r4 = __fadd_rn(r4, __fmul_rn(a[i + 4], a[i + 4]));
        r5 = __fadd_rn(r5, __fmul_rn(a[i + 5], a[i + 5]));
        r6 = __fadd_rn(r6, __fmul_rn(a[i + 6], a[i + 6]));
        r7 = __fadd_rn(r7, __fmul_rn(a[i + 7], a[i + 7]));
    }
    return __fadd_rn(__fadd_rn(__fadd_rn(r0, r1), __fadd_rn(r2, r3)),
                     __fadd_rn(__fadd_rn(r4, r5), __fadd_rn(r6, r7)));
}

// strided (z-layout) variant — identical op order to the validated vq_zsq.
__device__ __forceinline__ float np_sumsq64_strided(const float* zp) {
    float r[8];
#pragma unroll
    for (int j = 0; j < 8; ++j) {
        float v = zp[(size_t)j * DSTRIDE];
        r[j] = __fmul_rn(v, v);
    }
#pragma unroll
    for (int i = 8; i < 64; i += 8)
#pragma unroll
        for (int j = 0; j < 8; ++j) {
            float v = zp[(size_t)(i + j) * DSTRIDE];
            r[j] = __fadd_rn(r[j], __fmul_rn(v, v));
        }
    return __fadd_rn(__fadd_rn(__fadd_rn(r[0], r[1]), __fadd_rn(r[2], r[3])),
                     __fadd_rn(__fadd_rn(r[4], r[5]), __fadd_rn(r[6], r[7])));
}

// Merged: csq (numpy fp32) + bf16 hi/lo B-fragment prep + state zeroing.
// B frag for v_mfma_f32_16x16x32_bf16: col = lane&15, k = (lane>>4)*8 + j.
__global__ __launch_bounds__(256) void vq_prep(const float* __restrict__ cb,
                                               float* __restrict__ csq,
                                               unsigned short* __restrict__ cbB,
                                               double* __restrict__ acc,
                                               unsigned* __restrict__ done) {
    if (blockIdx.x == 0 && threadIdx.x == 0) {
        *acc = 0.0;
        *done = 0u;
    }
    int k = blockIdx.x * 256 + threadIdx.x;
    const float* cp = cb + k * DD;
    csq[k] = np_sumsq64(cp);
    int ct = k >> 4, col = k & 15;
#pragma unroll
    for (int d = 0; d < DD; ++d) {
        float c = cp[d];
        unsigned short hi = f2bf_rne(c);
        float hf = __uint_as_float((unsigned)hi << 16);
        unsigned short lo = f2bf_rne(c - hf);
        int s = d >> 5, lg = (d >> 3) & 3, j = d & 7;
        int lane = col + 16 * lg;
        int base = ct * 2048 + s * 512 + lane * 8 + j;
        cbB[base] = hi;          // h = 0
        cbB[base + 1024] = lo;   // h = 1
    }
}

// dist computation: two independent 3-chains.
#define MFMA_DIST(P, Q, A_H0, A_H1, A_L0, A_L1, B0, B1, B2, B3)               \
    P = __builtin_amdgcn_mfma_f32_16x16x32_bf16(A_H0, B0, P, 0, 0, 0);        \
    Q = __builtin_amdgcn_mfma_f32_16x16x32_bf16(A_H0, B2, Q, 0, 0, 0);        \
    P = __builtin_amdgcn_mfma_f32_16x16x32_bf16(A_H1, B1, P, 0, 0, 0);        \
    Q = __builtin_amdgcn_mfma_f32_16x16x32_bf16(A_H1, B3, Q, 0, 0, 0);        \
    P = __builtin_amdgcn_mfma_f32_16x16x32_bf16(A_L0, B0, P, 0, 0, 0);        \
    Q = __builtin_amdgcn_mfma_f32_16x16x32_bf16(A_L1, B1, Q, 0, 0, 0);

// fp64 reference-fp32-emulated distance (bit-identical to the validated
// refine of earlier rounds) -> order-preserving packed u64 (ties -> lowest k).
__device__ __forceinline__ unsigned long long ref_pack(const float* zp,
                                                       const float* cp,
                                                       float zsqn, float csqk,
                                                       unsigned k) {
    double a0 = 0.0, a1 = 0.0, a2 = 0.0, a3 = 0.0;
#pragma unroll
    for (int d = 0; d < DD; d += 4) {
        a0 = fma((double)zp[(size_t)(d + 0) * DSTRIDE], (double)cp[d + 0], a0);
        a1 = fma((double)zp[(size_t)(d + 1) * DSTRIDE], (double)cp[d + 1], a1);
        a2 = fma((double)zp[(size_t)(d + 2) * DSTRIDE], (double)cp[d + 2], a2);
        a3 = fma((double)zp[(size_t)(d + 3) * DSTRIDE], (double)cp[d + 3], a3);
    }
    double dot = (a0 + a1) + (a2 + a3);
    float twoC = (float)(2.0 * dot);               // ~sgemm output, correctly rounded
    float dist = __fsub_rn(__fadd_rn(zsqn, csqk), twoC);  // reference fp32 ops
    unsigned ub = __float_as_uint(dist);
    ub = (ub & 0x80000000u) ? ~ub : (ub | 0x80000000u);   // order-preserving map
    return ((unsigned long long)ub << 32) | k;
}

// -------- fully fused: MFMA scan + exact argmin + gather + loss --------
// block = 64 rows = 4 waves; wave w owns rows [16w,16w+16), scans all 1024
// codes (r4 hot loop verbatim: inline B loads, phase-locked every 8 ct,
// register min1/min2/bst). Post-loop, per row: g1 = 16-lane butterfly min;
// candidates = lane-bests with m1 < g1+TAU (ballot+popcount, no atomics).
// Error budget: |mfma - ref| <= ~3e-5; ref winner w has mfma(w) <= g1+6e-5
// < g1+TAU. If w is not its lane's best, that lane has m2 < g1+TAU ->
// ballot-detected -> full-1024 fp64 fallback for that row (~0.5% of rows).
// Exactly-1 candidate (most rows): provably the ref argmin, no fp64 needed.
// Multi-candidate rows: validated fp64 ref emulation on each candidate.
// Epilogue: gather z_q, write zq, block loss partial, last block finalizes.
__global__ __launch_bounds__(256)
void vq_fused(const float* __restrict__ z,
              const unsigned short* __restrict__ cbB,
              const float* __restrict__ cb,
              const float* __restrict__ csq,
              float* __restrict__ idxf_out,
              float* __restrict__ zq_out,
              float* __restrict__ loss_out,
              double* __restrict__ acc,
              unsigned* __restrict__ done) {
    __shared__ __align__(16) unsigned short aFrag[4][2][2][64][8];  // [rt][s][h][lane][j]
    __shared__ float scsq[1024];
    __shared__ int candCnt[64];
    __shared__ unsigned short candK[64][16];
    __shared__ unsigned char ovfF[64];
    __shared__ int ridx[64];
    __shared__ unsigned long long rpack[64];
    __shared__ int workRows[64];
    __shared__ int nWork;
    __shared__ float partial[4];

    int t = threadIdx.x;
    int n0 = blockIdx.x * 64;
    int b = n0 >> 12, p0 = n0 & 4095;   // 64 | 4096 -> no batch crossing in block

    for (int i = t; i < 1024; i += 256) scsq[i] = csq[i];
    if (t == 0) nWork = 0;
    if (t < 64) rpack[t] = ~0ull;

    {   // stage z tile: thread t loads row r = t&63, d-groups g = 2*(t>>6)+{0,1}
        int r = t & 63, gb = t >> 6;
        const float* zp = z + (size_t)b * BSTRIDE + p0 + r;
#pragma unroll
        for (int gg = 0; gg < 2; ++gg) {
            int g = (gb << 1) | gg;  // d in [8g, 8g+8)
            short8 hi8, lo8;
#pragma unroll
            for (int i2 = 0; i2 < 8; ++i2) {
                float v = zp[(size_t)(8 * g + i2) * DSTRIDE];  // coalesced across lanes
                unsigned short h = f2bf_rne(v);
                float hf = __uint_as_float((unsigned)h << 16);
                hi8[i2] = (short)h;
                lo8[i2] = (short)f2bf_rne(v - hf);
            }
            int rt = r >> 4, s = g >> 2, lane = (r & 15) + 16 * (g & 3);
            *(short8*)&aFrag[rt][s][0][lane][0] = hi8;
            *(short8*)&aFrag[rt][s][1][lane][0] = lo8;
        }
    }
    __syncthreads();

    int l = t & 63;
    int colcode = l & 15;
    int w = __builtin_amdgcn_readfirstlane(t >> 6);  // wave id = row-tile

    short8 aH0 = *(const short8*)&aFrag[w][0][0][l][0];
    short8 aH1 = *(const short8*)&aFrag[w][1][0][l][0];
    short8 aL0 = *(const short8*)&aFrag[w][0][1][l][0];
    short8 aL1 = *(const short8*)&aFrag[w][1][1][l][0];

    float m1[4], m2[4];
    int bst[4];
#pragma unroll
    for (int r = 0; r < 4; ++r) {
        m1[r] = 3.4e38f;
        m2[r] = 3.4e38f;
        bst[r] = 0;
    }

    // ---- r4-verbatim hot loop ----
    for (int ph = 0; ph < 8; ++ph) {
        __syncthreads();  // phase-lock the 4 waves for L1 B-frag reuse
#pragma unroll 2
        for (int c8 = 0; c8 < 8; ++c8) {
            int ct = (ph << 3) | c8;
            const unsigned short* bp = cbB + ct * 2048 + (l << 3);
            short8 b0 = *(const short8*)(bp);
            short8 b1 = *(const short8*)(bp + 512);
            short8 b2 = *(const short8*)(bp + 1024);
            short8 b3 = *(const short8*)(bp + 1536);
            float cs = scsq[(ct << 4) + colcode];
            int code = (ct << 4) + colcode;
            f32x4 p = {0.f, 0.f, 0.f, 0.f}, q = {0.f, 0.f, 0.f, 0.f};
            MFMA_DIST(p, q, aH0, aH1, aL0, aL1, b0, b1, b2, b3)
#pragma unroll
            for (int r = 0; r < 4; ++r) {
                float dist = fmaf(-2.f, p[r] + q[r], cs);
                bool lt = dist < m1[r];  // strict: ties keep lowest code
                m2[r] = lt ? m1[r] : fminf(m2[r], dist);
                bst[r] = lt ? code : bst[r];
                m1[r] = lt ? dist : m1[r];
            }
        }
    }

    // ---- candidate extraction: g1 butterfly + ballots (no hot-loop cost) ----
    int g = l >> 4;  // lane group; lanes [16g,16g+16) share rows 4g+0..4g+3
#pragma unroll
    for (int r = 0; r < 4; ++r) {
        float v = m1[r];
        v = fminf(v, __shfl_xor(v, 1, 64));
        v = fminf(v, __shfl_xor(v, 2, 64));
        v = fminf(v, __shfl_xor(v, 4, 64));
        v = fminf(v, __shfl_xor(v, 8, 64));
        float thr = v + TAU;
        bool mine = (m1[r] < thr);
        unsigned long long bal1 = __ballot(mine);
        unsigned long long bal2 = __ballot(m2[r] < thr);
        unsigned slice1 = (unsigned)((bal1 >> (16 * g)) & 0xFFFFull);
        unsigned slice2 = (unsigned)((bal2 >> (16 * g)) & 0xFFFFull);
        int row = (w << 4) + (g << 2) + r;
        if (mine) {
            int pos = __popc(slice1 & ((1u << colcode) - 1u));
            candK[row][pos] = (unsigned short)bst[r];
        }
        if (colcode == 0) {
            candCnt[row] = __popc(slice1);
            ovfF[row] = (slice2 != 0u) ? 1 : 0;
        }
    }
    __syncthreads();

    if (t < 64) {
        int cnt = candCnt[t];
        if (cnt == 1 && !ovfF[t]) {
            ridx[t] = candK[t][0];          // provably the ref argmin
        } else {
            int wi = atomicAdd(&nWork, 1);  // needs fp64 resolution
            workRows[wi] = t;
        }
    }
    __syncthreads();

    // ---- fp64 reference emulation for ambiguous rows ----
    int nw = nWork;
    for (int wi0 = 0; wi0 < nw; wi0 += 16) {
        int wi = wi0 + (t >> 4);
        if (wi < nw) {
            int row = workRows[wi];
            int c = t & 15;
            if (!ovfF[row] && c < candCnt[row]) {
                unsigned k = candK[row][c];
                const float* zp = z + (size_t)b * BSTRIDE + p0 + row;
                float zsqn = np_sumsq64_strided(zp);
                unsigned long long pk =
                    ref_pack(zp, cb + k * DD, zsqn, scsq[k], k);
                atomicMin(&rpack[row], pk);
            }
        }
    }
    for (int wi = 0; wi < nw; ++wi) {       // overflow rows: full 1024 scan
        int row = workRows[wi];
        if (ovfF[row]) {
            const float* zp = z + (size_t)b * BSTRIDE + p0 + row;
            float zsqn = np_sumsq64_strided(zp);
            for (unsigned k = (unsigned)t; k < 1024u; k += 256u) {
                unsigned long long pk =
                    ref_pack(zp, cb + k * DD, zsqn, scsq[k], k);
                atomicMin(&rpack[row], pk);
            }
        }
    }
    __syncthreads();
    if (t < 64) {
        if (rpack[t] != ~0ull) ridx[t] = (int)(unsigned)(rpack[t] & 1023ull);
        idxf_out[n0 + t] = (float)ridx[t];
    }
    __syncthreads();

    // ---- fused gather z_q + loss (rows L2-warm, coalesced across lanes) ----
    {
        int r = t & 63, dg = t >> 6;   // 16 d's per thread
        int kk = ridx[r];
        const float* zp = z + (size_t)b * BSTRIDE + p0 + r;
        float* qp = zq_out + (size_t)b * BSTRIDE + p0 + r;
        const float* cp = cb + kk * DD;
        float s = 0.f;
#pragma unroll
        for (int dd = dg * 16; dd < dg * 16 + 16; ++dd) {
            float qv = cp[dd];
            float diff = qv - zp[(size_t)dd * DSTRIDE];
            s = fmaf(diff, diff, s);
            qp[(size_t)dd * DSTRIDE] = qv;  // z_q_st == z_q numerically
        }
#pragma unroll
        for (int off = 32; off; off >>= 1) s += __shfl_down(s, off, 64);
        if (l == 0) partial[t >> 6] = s;
    }
    __syncthreads();
    if (t == 0) {
        float tt = (partial[0] + partial[1]) + (partial[2] + partial[3]);
        atomicAdd(acc, (double)tt);
        __threadfence();
        unsigned v = atomicAdd(done, 1u);
        if (v == gridDim.x - 1) {           // last block finalizes the loss
            __threadfence();
            double s2 = atomicAdd(acc, 0.0);
            *loss_out = (float)(1.25 * s2 / (double)ZQ_ELEMS);
        }
    }
}

extern "C" void kernel_launch(void* const* d_in, const int* in_sizes, int n_in,
                              void* d_out, int out_size, void* d_ws, size_t ws_size,
                              hipStream_t stream) {
    const float* z = (const float*)d_in[0];
    const float* cb = (const float*)d_in[1];
    float* out = (float*)d_out;

    float* zq_out = out;                   // [0, 8388608)
    float* loss_out = out + ZQ_ELEMS;      // [8388608]
    float* idxf_out = out + ZQ_ELEMS + 1;  // [8388609, +131072)

    char* ws = (char*)d_ws;
    double* acc = (double*)ws;
    unsigned* done = (unsigned*)(ws + 8);
    float* csq = (float*)(ws + WS_CSQ_OFF);
    unsigned short* cbB = (unsigned short*)(ws + WS_CBB_OFF);

    vq_prep<<<KK / 256, 256, 0, stream>>>(cb, csq, cbB, acc, done);
    vq_fused<<<ZN / 64, 256, 0, stream>>>(z, cbB, cb, csq, idxf_out,
                                          zq_out, loss_out, acc, done);
}